// Round 4
// baseline (230.430 us; speedup 1.0000x reference)
//
#include <hip/hip_runtime.h>
#include <hip/hip_cooperative_groups.h>
#include <math.h>

namespace cg = cooperative_groups;

#define KEYS 11
#define NSTACK 4
#define NB 16
#define HH 128
#define WW 128
#define HW (HH * WW)
#define NGRP (NB * KEYS)        // 176
#define NCHUNK 4
#define CF4 (HW / 4 / NCHUNK)   // 1024 f4 elements per chunk
#define NBLK (NGRP * NCHUNK)    // 704

typedef float f4 __attribute__((ext_vector_type(4)));

// ws layout (floats); total 16896 floats = 67.6 KB
//   [0, 11264)      partial records: f4 {sum, vmax, imax(bits), 0} at [(g*4+s)*4 + c]
//   [11264, 16896)  label-prep:      2x f4 {q1,q2,lb7,lb8},{cls,valid,0,0} at [(g*4+s)*2]
#define WS_LP (NBLK * NSTACK * 4)

// ---- chunk work: stream 1/4 of the (b,k) planes for all 4 stacks ----
__device__ __forceinline__ void do_chunk(
    const float* __restrict__ cp, const float* __restrict__ heat,
    const float* __restrict__ lab, float* __restrict__ ws,
    int bid, int tid)
{
    const int c   = bid & (NCHUNK - 1);   // chunk fastest-varying
    const int grp = bid >> 2;             // b*KEYS + k
    const int b = grp / KEYS;
    const int k = grp % KEYS;

    const int coff = c * CF4;
    const f4* __restrict__ ht4 = (const f4*)(heat + (size_t)grp * HW) + coff;
    const f4* __restrict__ hm0 = (const f4*)(cp + ((size_t)((b * NSTACK + 0) * (2 * KEYS) + k)) * HW) + coff;
    const f4* __restrict__ hm1 = (const f4*)(cp + ((size_t)((b * NSTACK + 1) * (2 * KEYS) + k)) * HW) + coff;
    const f4* __restrict__ hm2 = (const f4*)(cp + ((size_t)((b * NSTACK + 2) * (2 * KEYS) + k)) * HW) + coff;
    const f4* __restrict__ hm3 = (const f4*)(cp + ((size_t)((b * NSTACK + 3) * (2 * KEYS) + k)) * HW) + coff;

    float sum[NSTACK]  = {0.0f, 0.0f, 0.0f, 0.0f};
    float vmax[NSTACK] = {-INFINITY, -INFINITY, -INFINITY, -INFINITY};
    int   imax[NSTACK] = {0, 0, 0, 0};

    #pragma unroll
    for (int i = tid; i < CF4; i += 256) {   // 4 iterations, fully unrolled: 20 nt loads in flight
        f4 cv = __builtin_nontemporal_load(ht4 + i);
        f4 a[NSTACK];
        a[0] = __builtin_nontemporal_load(hm0 + i);
        a[1] = __builtin_nontemporal_load(hm1 + i);
        a[2] = __builtin_nontemporal_load(hm2 + i);
        a[3] = __builtin_nontemporal_load(hm3 + i);
        const int base = (coff + i) * 4;
        #pragma unroll
        for (int s = 0; s < NSTACK; ++s) {
            float d0 = a[s][0] - cv[0], d1 = a[s][1] - cv[1];
            float d2 = a[s][2] - cv[2], d3 = a[s][3] - cv[3];
            sum[s] += d0 * d0 + d1 * d1 + d2 * d2 + d3 * d3;
            // strictly-greater keeps first occurrence (indices increase per thread)
            if (a[s][0] > vmax[s]) { vmax[s] = a[s][0]; imax[s] = base;     }
            if (a[s][1] > vmax[s]) { vmax[s] = a[s][1]; imax[s] = base + 1; }
            if (a[s][2] > vmax[s]) { vmax[s] = a[s][2]; imax[s] = base + 2; }
            if (a[s][3] > vmax[s]) { vmax[s] = a[s][3]; imax[s] = base + 3; }
        }
    }

    // wave-64 reduction per stack (sum + argmax with first-index tie break)
    #pragma unroll
    for (int off = 32; off > 0; off >>= 1) {
        #pragma unroll
        for (int s = 0; s < NSTACK; ++s) {
            float ov = __shfl_down(vmax[s], off);
            int   oi = __shfl_down(imax[s], off);
            float os = __shfl_down(sum[s],  off);
            sum[s] += os;
            if (ov > vmax[s] || (ov == vmax[s] && oi < imax[s])) { vmax[s] = ov; imax[s] = oi; }
        }
    }

    __shared__ float s_sum[4][NSTACK];
    __shared__ float s_v[4][NSTACK];
    __shared__ int   s_i[4][NSTACK];
    const int wave = tid >> 6;
    if ((tid & 63) == 0) {
        #pragma unroll
        for (int s = 0; s < NSTACK; ++s) {
            s_sum[wave][s] = sum[s]; s_v[wave][s] = vmax[s]; s_i[wave][s] = imax[s];
        }
    }
    __syncthreads();

    if (tid < NSTACK) {
        const int s = tid;
        float fsum = s_sum[0][s];
        float fv   = s_v[0][s];
        int   fi   = s_i[0][s];
        #pragma unroll
        for (int w = 1; w < 4; w++) {
            fsum += s_sum[w][s];
            if (s_v[w][s] > fv || (s_v[w][s] == fv && s_i[w][s] < fi)) {
                fv = s_v[w][s]; fi = s_i[w][s];
            }
        }
        f4 rec; rec[0] = fsum; rec[1] = fv; rec[2] = __int_as_float(fi); rec[3] = 0.0f;
        ((f4*)ws)[(size_t)(grp * NSTACK + s) * NCHUNK + c] = rec;

        if (c == 0) {
            // argmax-independent label prep for (b, s, k): scattered reads are
            // spread over 176 blocks and hidden under the streaming loop.
            const float* __restrict__ lb = cp + ((size_t)((b * NSTACK + s) * (2 * KEYS) + KEYS + k)) * HW;
            const float* __restrict__ L  = lab + (size_t)grp * 11;
            float gx = L[9], gy = L[10];
            bool valid = (gx > 0.0f) && (gy > 0.0f) && (gx < (float)HH) && (gy < (float)WW);
            float cls = 0.0f;
            #pragma unroll
            for (int j = 0; j < 7; j++) {
                float d = lb[j] - L[j];
                cls += d * d;
            }
            f4 a; a[0] = gx + L[7]; a[1] = gy + L[8]; a[2] = lb[7]; a[3] = lb[8];
            f4 bb; bb[0] = cls; bb[1] = valid ? 1.0f : 0.0f; bb[2] = 0.0f; bb[3] = 0.0f;
            f4* lp = (f4*)(ws + WS_LP);
            lp[(size_t)(grp * NSTACK + s) * 2 + 0] = a;
            lp[(size_t)(grp * NSTACK + s) * 2 + 1] = bb;
        }
    }
}

// ---- finalize: combine chunks (ascending -> first-occurrence exact), label
// loss from staged prep, deterministic ascending-k output sums. Reads ONLY ws.
__device__ __forceinline__ void do_final(
    const float* __restrict__ ws, float* __restrict__ out, int tid)
{
    __shared__ float sh[NGRP * NSTACK];
    __shared__ float sl[NGRP * NSTACK];

    for (int idx = tid; idx < NGRP * NSTACK; idx += 256) {
        const f4* pr = (const f4*)ws + (size_t)idx * NCHUNK;  // 64B contiguous
        float fsum = 0.0f, fv = -INFINITY;
        int   fi = 0;
        #pragma unroll
        for (int c = 0; c < NCHUNK; ++c) {
            f4 r = pr[c];
            fsum += r[0];
            float pv = r[1];
            int   pi = __float_as_int(r[2]);
            if (pv > fv || (pv == fv && pi < fi)) { fv = pv; fi = pi; }
        }
        sh[idx] = fsum;

        const f4* lp = (const f4*)(ws + WS_LP) + (size_t)idx * 2;
        f4 a = lp[0], bb = lp[1];
        float loss = 0.0f;
        if (bb[1] != 0.0f) {
            float xf = (float)(fi / WW);     // row
            float yf = (float)(fi % WW);     // col
            float dx = (a[0] - xf) - a[2];   // ((gx+L7) - xf) - lb7: original order
            float dy = (a[1] - yf) - a[3];
            loss = dx * dx + dy * dy;
            float cm = 1.0f - fv;
            loss += cm * cm;
            loss += bb[0];                   // class term
        }
        sl[idx] = loss;
    }
    __syncthreads();

    if (tid < NB * NSTACK) {                 // 64 outputs
        const int b = tid >> 2;
        const int s = tid & 3;
        float h = 0.0f, l = 0.0f;
        #pragma unroll
        for (int k = 0; k < KEYS; ++k) {
            const int g = b * KEYS + k;
            h += sh[g * NSTACK + s];
            l += sl[g * NSTACK + s];
        }
        out[tid] = h;
        out[64 + tid] = l;
    }
}

// ---- single fused dispatch (cooperative) ----
__global__ __launch_bounds__(256, 3) void kp_fused(
    const float* __restrict__ cp, const float* __restrict__ heat,
    const float* __restrict__ lab, float* __restrict__ ws, float* __restrict__ out)
{
    do_chunk(cp, heat, lab, ws, blockIdx.x, threadIdx.x);
    __threadfence();
    cg::this_grid().sync();
    if (blockIdx.x == 0) do_final(ws, out, threadIdx.x);
}

// ---- fallback 2-dispatch path (identical math) ----
__global__ __launch_bounds__(256) void kp_main2(
    const float* __restrict__ cp, const float* __restrict__ heat,
    const float* __restrict__ lab, float* __restrict__ ws)
{
    do_chunk(cp, heat, lab, ws, blockIdx.x, threadIdx.x);
}

__global__ __launch_bounds__(256) void kp_final2(
    const float* __restrict__ ws, float* __restrict__ out)
{
    do_final(ws, out, threadIdx.x);
}

extern "C" void kernel_launch(void* const* d_in, const int* in_sizes, int n_in,
                              void* d_out, int out_size, void* d_ws, size_t ws_size,
                              hipStream_t stream) {
    const float* cp   = (const float*)d_in[0];
    const float* heat = (const float*)d_in[1];
    const float* lab  = (const float*)d_in[2];
    float* out = (float*)d_out;
    float* ws  = (float*)d_ws;   // needs 16896 floats = 67.6 KB

    static int use_coop = -1;
    if (use_coop < 0) {
        int maxb = 0;
        hipError_t e = hipOccupancyMaxActiveBlocksPerMultiprocessor(&maxb, kp_fused, 256, 0);
        // MI355X: 256 CUs; need all 704 blocks co-resident
        use_coop = (e == hipSuccess && maxb * 256 >= NBLK) ? 1 : 0;
    }
    if (use_coop) {
        void* args[] = {(void*)&cp, (void*)&heat, (void*)&lab, (void*)&ws, (void*)&out};
        hipError_t e = hipLaunchCooperativeKernel((const void*)kp_fused,
                                                  dim3(NBLK), dim3(256), args, 0, stream);
        if (e != hipSuccess) use_coop = 0;   // fall through to 2-kernel path
    }
    if (!use_coop) {
        kp_main2<<<NBLK, 256, 0, stream>>>(cp, heat, lab, ws);
        kp_final2<<<1, 256, 0, stream>>>(ws, out);
    }
}

// Round 5
// 147.273 us; speedup vs baseline: 1.5646x; 1.5646x over previous
//
#include <hip/hip_runtime.h>
#include <math.h>

#define KEYS 11
#define NSTACK 4
#define NB 16
#define HH 128
#define WW 128
#define HW (HH * WW)
#define NGRP (NB * KEYS)        // 176
#define NCHUNK 4
#define CF4 (HW / 4 / NCHUNK)   // 1024 f4 elements per chunk
#define NBLK (NGRP * NCHUNK)    // 704

typedef float f4 __attribute__((ext_vector_type(4)));

// ws layout (floats); total 16896 floats = 67.6 KB
//   [0, 11264)      partial records: f4 {sum, vmax, imax(bits), 0} at [(g*4+s)*4 + c]
//   [11264, 16896)  label-prep:      2x f4 {q1,q2,lb7,lb8},{cls,valid,0,0} at [(g*4+s)*2]
#define WS_LP (NBLK * NSTACK * 4)

// Fan-in counter. Module-load zero-initialized; the finalizing block resets it
// to 0, so the invariant (counter==0 at launch) holds across graph replays.
__device__ int g_done = 0;

// ---- chunk work: stream 1/4 of the (b,k) planes for all 4 stacks ----
__device__ __forceinline__ void do_chunk(
    const float* __restrict__ cp, const float* __restrict__ heat,
    const float* __restrict__ lab, float* __restrict__ ws,
    int bid, int tid)
{
    const int c   = bid & (NCHUNK - 1);   // chunk fastest-varying
    const int grp = bid >> 2;             // b*KEYS + k
    const int b = grp / KEYS;
    const int k = grp % KEYS;

    const int coff = c * CF4;
    const f4* __restrict__ ht4 = (const f4*)(heat + (size_t)grp * HW) + coff;
    const f4* __restrict__ hm0 = (const f4*)(cp + ((size_t)((b * NSTACK + 0) * (2 * KEYS) + k)) * HW) + coff;
    const f4* __restrict__ hm1 = (const f4*)(cp + ((size_t)((b * NSTACK + 1) * (2 * KEYS) + k)) * HW) + coff;
    const f4* __restrict__ hm2 = (const f4*)(cp + ((size_t)((b * NSTACK + 2) * (2 * KEYS) + k)) * HW) + coff;
    const f4* __restrict__ hm3 = (const f4*)(cp + ((size_t)((b * NSTACK + 3) * (2 * KEYS) + k)) * HW) + coff;

    float sum[NSTACK]  = {0.0f, 0.0f, 0.0f, 0.0f};
    float vmax[NSTACK] = {-INFINITY, -INFINITY, -INFINITY, -INFINITY};
    int   imax[NSTACK] = {0, 0, 0, 0};

    #pragma unroll
    for (int i = tid; i < CF4; i += 256) {   // 4 iterations, fully unrolled: 20 nt loads in flight
        f4 cv = __builtin_nontemporal_load(ht4 + i);
        f4 a[NSTACK];
        a[0] = __builtin_nontemporal_load(hm0 + i);
        a[1] = __builtin_nontemporal_load(hm1 + i);
        a[2] = __builtin_nontemporal_load(hm2 + i);
        a[3] = __builtin_nontemporal_load(hm3 + i);
        const int base = (coff + i) * 4;
        #pragma unroll
        for (int s = 0; s < NSTACK; ++s) {
            float d0 = a[s][0] - cv[0], d1 = a[s][1] - cv[1];
            float d2 = a[s][2] - cv[2], d3 = a[s][3] - cv[3];
            sum[s] += d0 * d0 + d1 * d1 + d2 * d2 + d3 * d3;
            // strictly-greater keeps first occurrence (indices increase per thread)
            if (a[s][0] > vmax[s]) { vmax[s] = a[s][0]; imax[s] = base;     }
            if (a[s][1] > vmax[s]) { vmax[s] = a[s][1]; imax[s] = base + 1; }
            if (a[s][2] > vmax[s]) { vmax[s] = a[s][2]; imax[s] = base + 2; }
            if (a[s][3] > vmax[s]) { vmax[s] = a[s][3]; imax[s] = base + 3; }
        }
    }

    // wave-64 reduction per stack (sum + argmax with first-index tie break)
    #pragma unroll
    for (int off = 32; off > 0; off >>= 1) {
        #pragma unroll
        for (int s = 0; s < NSTACK; ++s) {
            float ov = __shfl_down(vmax[s], off);
            int   oi = __shfl_down(imax[s], off);
            float os = __shfl_down(sum[s],  off);
            sum[s] += os;
            if (ov > vmax[s] || (ov == vmax[s] && oi < imax[s])) { vmax[s] = ov; imax[s] = oi; }
        }
    }

    __shared__ float s_sum[4][NSTACK];
    __shared__ float s_v[4][NSTACK];
    __shared__ int   s_i[4][NSTACK];
    const int wave = tid >> 6;
    if ((tid & 63) == 0) {
        #pragma unroll
        for (int s = 0; s < NSTACK; ++s) {
            s_sum[wave][s] = sum[s]; s_v[wave][s] = vmax[s]; s_i[wave][s] = imax[s];
        }
    }
    __syncthreads();

    if (tid < NSTACK) {
        const int s = tid;
        float fsum = s_sum[0][s];
        float fv   = s_v[0][s];
        int   fi   = s_i[0][s];
        #pragma unroll
        for (int w = 1; w < 4; w++) {
            fsum += s_sum[w][s];
            if (s_v[w][s] > fv || (s_v[w][s] == fv && s_i[w][s] < fi)) {
                fv = s_v[w][s]; fi = s_i[w][s];
            }
        }
        f4 rec; rec[0] = fsum; rec[1] = fv; rec[2] = __int_as_float(fi); rec[3] = 0.0f;
        ((f4*)ws)[(size_t)(grp * NSTACK + s) * NCHUNK + c] = rec;

        if (c == 0) {
            // argmax-independent label prep for (b, s, k): scattered reads are
            // spread over 176 blocks and hidden under the streaming loop.
            const float* __restrict__ lb = cp + ((size_t)((b * NSTACK + s) * (2 * KEYS) + KEYS + k)) * HW;
            const float* __restrict__ L  = lab + (size_t)grp * 11;
            float gx = L[9], gy = L[10];
            bool valid = (gx > 0.0f) && (gy > 0.0f) && (gx < (float)HH) && (gy < (float)WW);
            float cls = 0.0f;
            #pragma unroll
            for (int j = 0; j < 7; j++) {
                float d = lb[j] - L[j];
                cls += d * d;
            }
            f4 a; a[0] = gx + L[7]; a[1] = gy + L[8]; a[2] = lb[7]; a[3] = lb[8];
            f4 bb; bb[0] = cls; bb[1] = valid ? 1.0f : 0.0f; bb[2] = 0.0f; bb[3] = 0.0f;
            f4* lp = (f4*)(ws + WS_LP);
            lp[(size_t)(grp * NSTACK + s) * 2 + 0] = a;
            lp[(size_t)(grp * NSTACK + s) * 2 + 1] = bb;
        }
    }
}

// ---- finalize: combine chunks (ascending -> first-occurrence exact), label
// loss from staged prep, deterministic ascending-k output sums. Reads ONLY ws.
__device__ __forceinline__ void do_final(
    const float* __restrict__ ws, float* __restrict__ out, int tid)
{
    __shared__ float sh[NGRP * NSTACK];
    __shared__ float sl[NGRP * NSTACK];

    for (int idx = tid; idx < NGRP * NSTACK; idx += 256) {
        const f4* pr = (const f4*)ws + (size_t)idx * NCHUNK;  // 64B contiguous
        float fsum = 0.0f, fv = -INFINITY;
        int   fi = 0;
        #pragma unroll
        for (int c = 0; c < NCHUNK; ++c) {
            f4 r = pr[c];
            fsum += r[0];
            float pv = r[1];
            int   pi = __float_as_int(r[2]);
            if (pv > fv || (pv == fv && pi < fi)) { fv = pv; fi = pi; }
        }
        sh[idx] = fsum;

        const f4* lp = (const f4*)(ws + WS_LP) + (size_t)idx * 2;
        f4 a = lp[0], bb = lp[1];
        float loss = 0.0f;
        if (bb[1] != 0.0f) {
            float xf = (float)(fi / WW);     // row
            float yf = (float)(fi % WW);     // col
            float dx = (a[0] - xf) - a[2];   // ((gx+L7) - xf) - lb7: original order
            float dy = (a[1] - yf) - a[3];
            loss = dx * dx + dy * dy;
            float cm = 1.0f - fv;
            loss += cm * cm;
            loss += bb[0];                   // class term
        }
        sl[idx] = loss;
    }
    __syncthreads();

    if (tid < NB * NSTACK) {                 // 64 outputs
        const int b = tid >> 2;
        const int s = tid & 3;
        float h = 0.0f, l = 0.0f;
        #pragma unroll
        for (int k = 0; k < KEYS; ++k) {
            const int g = b * KEYS + k;
            h += sh[g * NSTACK + s];
            l += sl[g * NSTACK + s];
        }
        out[tid] = h;
        out[64 + tid] = l;
    }
}

// ---- single dispatch: chunk work + last-block fan-in finalize ----
// No cooperative launch, no grid-wide spin: non-last blocks exit after one
// device-scope atomicAdd. The last block acquires (L2-invalidate across XCDs
// via __threadfence) and finalizes.
__global__ __launch_bounds__(256) void kp_fused(
    const float* __restrict__ cp, const float* __restrict__ heat,
    const float* __restrict__ lab, float* __restrict__ ws, float* __restrict__ out)
{
    do_chunk(cp, heat, lab, ws, blockIdx.x, threadIdx.x);

    __shared__ int is_last;
    __syncthreads();                       // all ws stores issued (each wave's
                                           // stores drained by its barrier entry)
    if (threadIdx.x == 0) {
        __threadfence();                   // release: write back dirty L2 to device scope
        int v = atomicAdd(&g_done, 1);     // device-scope by default
        is_last = (v == NBLK - 1);
        if (is_last) g_done = 0;           // all arrivals observed; safe to reset
    }
    __syncthreads();

    if (is_last) {
        __threadfence();                   // acquire: invalidate stale L2 lines in this XCD
        do_final(ws, out, threadIdx.x);
    }
}

extern "C" void kernel_launch(void* const* d_in, const int* in_sizes, int n_in,
                              void* d_out, int out_size, void* d_ws, size_t ws_size,
                              hipStream_t stream) {
    const float* cp   = (const float*)d_in[0];
    const float* heat = (const float*)d_in[1];
    const float* lab  = (const float*)d_in[2];
    float* out = (float*)d_out;
    float* ws  = (float*)d_ws;   // needs 16896 floats = 67.6 KB

    kp_fused<<<NBLK, 256, 0, stream>>>(cp, heat, lab, ws, out);
}

// Round 6
// 133.632 us; speedup vs baseline: 1.7244x; 1.1021x over previous
//
#include <hip/hip_runtime.h>
#include <math.h>

#define KEYS 11
#define NSTACK 4
#define NB 16
#define HH 128
#define WW 128
#define HW (HH * WW)

// native vector type so __builtin_nontemporal_load lowers to a 16B nt load
typedef float f4 __attribute__((ext_vector_type(4)));

__global__ void kp_zero_out(float* out) {
    out[threadIdx.x] = 0.0f;  // 128 output floats
}

__global__ __launch_bounds__(256) void kp_loss_kernel(
    const float* __restrict__ cp,    // (16, 4, 22, 128, 128)
    const float* __restrict__ heat,  // (16, 11, 128, 128)
    const float* __restrict__ lab,   // (16, 11, 11)
    float* __restrict__ out)         // 128: heat_loss(64) then label_loss(64)
{
    // XCD-aware decode: grid = 704 blocks, 8 XCDs round-robin on blockIdx%8.
    // Per XCD: 88 blocks = 22 (b,k) groups x 4 stacks. Each XCD owns exactly
    // 2 b-values (22 = 2*KEYS) -> heat working set/XCD = 22*64KB = 1.4MB < 4MB L2.
    // All 4 stacks of a (b,k) share one XCD => heat fetched from HBM once, L2-hit 3x.
    const int g   = blockIdx.x;
    const int xcd = g & 7;               // assumed XCD id (perf-only assumption)
    const int j   = g >> 3;              // 0..87 within XCD
    const int s   = j & 3;
    const int grp = xcd * 22 + (j >> 2); // 0..175  == b*KEYS + k
    const int b   = grp / KEYS;
    const int k   = grp % KEYS;
    const int bs  = b * NSTACK + s;

    const float* __restrict__ hm = cp + ((size_t)((bs) * (2 * KEYS) + k)) * HW;
    const float* __restrict__ ht = heat + ((size_t)(b * KEYS + k)) * HW;

    const int tid = threadIdx.x;
    float sum  = 0.0f;
    float vmax = -INFINITY;
    int   imax = 0;

    const f4* __restrict__ hm4 = (const f4*)hm;
    const f4* __restrict__ ht4 = (const f4*)ht;

    #pragma unroll 4
    for (int i = tid; i < HW / 4; i += 256) {
        f4 a = __builtin_nontemporal_load(hm4 + i);  // hm is read exactly once: stream it
        f4 c = ht4[i];                               // heat is reused 4x: keep cached
        float d0 = a[0] - c[0], d1 = a[1] - c[1], d2 = a[2] - c[2], d3 = a[3] - c[3];
        sum += d0 * d0 + d1 * d1 + d2 * d2 + d3 * d3;
        int base = i * 4;
        // strictly-greater keeps first occurrence (indices increase per thread)
        if (a[0] > vmax) { vmax = a[0]; imax = base;     }
        if (a[1] > vmax) { vmax = a[1]; imax = base + 1; }
        if (a[2] > vmax) { vmax = a[2]; imax = base + 2; }
        if (a[3] > vmax) { vmax = a[3]; imax = base + 3; }
    }

    // wave-64 reduction (sum + argmax with first-index tie break)
    #pragma unroll
    for (int off = 32; off > 0; off >>= 1) {
        float ov = __shfl_down(vmax, off);
        int   oi = __shfl_down(imax, off);
        float os = __shfl_down(sum,  off);
        sum += os;
        if (ov > vmax || (ov == vmax && oi < imax)) { vmax = ov; imax = oi; }
    }

    __shared__ float s_sum[4];
    __shared__ float s_v[4];
    __shared__ int   s_i[4];
    const int wave = tid >> 6;
    if ((tid & 63) == 0) { s_sum[wave] = sum; s_v[wave] = vmax; s_i[wave] = imax; }
    __syncthreads();

    if (tid == 0) {
        #pragma unroll
        for (int w = 1; w < 4; w++) {
            sum += s_sum[w];
            if (s_v[w] > vmax || (s_v[w] == vmax && s_i[w] < imax)) {
                vmax = s_v[w]; imax = s_i[w];
            }
        }
        atomicAdd(&out[bs], sum);

        // ---- label loss for this (b, s, k) ----
        const float* __restrict__ lb = cp + ((size_t)((bs) * (2 * KEYS) + KEYS + k)) * HW;
        const float* __restrict__ L  = lab + (size_t)(b * KEYS + k) * 11;
        float gx = L[9], gy = L[10];
        bool valid = (gx > 0.0f) && (gy > 0.0f) && (gx < (float)HH) && (gy < (float)WW);
        if (valid) {
            float xf = (float)(imax / WW);   // row (x = index // m, m == W == 128)
            float yf = (float)(imax % WW);   // col
            float dx = gx + L[7] - xf - lb[7];
            float dy = gy + L[8] - yf - lb[8];
            float loss = dx * dx + dy * dy;
            float cm = 1.0f - vmax;
            loss += cm * cm;
            #pragma unroll
            for (int j2 = 0; j2 < 7; j2++) {
                float d = lb[j2] - L[j2];
                loss += d * d;
            }
            atomicAdd(&out[64 + bs], loss);
        }
    }
}

extern "C" void kernel_launch(void* const* d_in, const int* in_sizes, int n_in,
                              void* d_out, int out_size, void* d_ws, size_t ws_size,
                              hipStream_t stream) {
    const float* cp   = (const float*)d_in[0];
    const float* heat = (const float*)d_in[1];
    const float* lab  = (const float*)d_in[2];
    float* out = (float*)d_out;

    kp_zero_out<<<1, 128, 0, stream>>>(out);
    kp_loss_kernel<<<NB * NSTACK * KEYS, 256, 0, stream>>>(cp, heat, lab, out);
}